// Round 1
// 488.239 us; speedup vs baseline: 1.3773x; 1.3773x over previous
//
#include <hip/hip_runtime.h>
#include <hip/hip_bf16.h>

#define N_NODES 50000
#define N_EDGES 800000
#define IN_DIM 64
#define HID_DIM 128
#define OUT_DIM 64
#define SCAN_T 1024
#define CHUNK ((N_NODES + SCAN_T - 1) / SCAN_T)  // 49

// ---- device-global scratch (no ws_size dependence) ----
__device__ int g_in_f32;
__device__ int g_is64;
__device__ int g_src[N_EDGES];
__device__ int g_dst[N_EDGES];
__device__ int g_csr[N_EDGES];
__device__ int g_deg[N_NODES];
__device__ int g_rowptr[N_NODES + 1];
__device__ int g_cursor[N_NODES];
__device__ float g_dinv[N_NODES];
__device__ __align__(16) float g_hs1[(size_t)N_NODES * HID_DIM];   // aggz (N*64), later hs2 (N*64)
__device__ __align__(16) float g_agg1[(size_t)N_NODES * HID_DIM];  // zs (N*64), later h (N*128)

__device__ __forceinline__ float loadx(const void* p, int i, int f32) {
    if (f32) return ((const float*)p)[i];
    unsigned int u = ((unsigned int)((const unsigned short*)p)[i]) << 16;
    return __uint_as_float(u);
}

// ---- dtype / index-width detection (data-driven, deterministic); zero deg ----
__global__ void detect_kernel(const unsigned short* __restrict__ zw,
                              const unsigned int* __restrict__ ew, int E) {
    __shared__ int s_f32, s_nz;
    if (threadIdx.x == 0) { s_f32 = 0; s_nz = 0; }
    __syncthreads();
    int hit = 0;
    for (int k = 0; k < 64; k++) {
        int i = 2 * ((threadIdx.x * 64 + k) * 97);
        if (((zw[i] >> 7) & 0xFF) == 0xFF) hit = 1;
    }
    if (hit) atomicOr(&s_f32, 1);
    int nz = 0;
    int step = E / 4096;
    for (int k = 0; k < 4; k++) {
        int idx = 1 + 2 * ((threadIdx.x * 4 + k) * step);
        if (ew[idx] != 0) nz = 1;
    }
    if (nz) atomicOr(&s_nz, 1);
    for (int i = threadIdx.x; i < N_NODES; i += 256) g_deg[i] = 0;
    __syncthreads();
    if (threadIdx.x == 0) { g_in_f32 = s_f32; g_is64 = (s_nz == 0) ? 1 : 0; }
}

// ---- normalize edge_index to int32 + fused degree count ----
__global__ void convert_kernel(const void* __restrict__ ei, int E) {
    int e = blockIdx.x * blockDim.x + threadIdx.x;
    if (e < E) {
        int s, d;
        if (g_is64) {
            const long long* p = (const long long*)ei;
            s = (int)p[e];
            d = (int)p[E + e];
        } else {
            const int* p = (const int*)ei;
            s = p[e];
            d = p[E + e];
        }
        g_src[e] = s;
        g_dst[e] = d;
        atomicAdd(&g_deg[d], 1);
    }
}

// ---- single-block exclusive scan of deg -> rowptr + cursor; dinv fused ----
__global__ __launch_bounds__(SCAN_T) void scan_kernel(int N, int E) {
    __shared__ int part[SCAN_T];
    int t = threadIdx.x;
    int beg = t * CHUNK, end = min(beg + CHUNK, N);
    int s = 0;
    for (int i = beg; i < end; i++) s += g_deg[i];
    part[t] = s;
    __syncthreads();
    for (int off = 1; off < SCAN_T; off <<= 1) {
        int v = (t >= off) ? part[t - off] : 0;
        __syncthreads();
        part[t] += v;
        __syncthreads();
    }
    int base = (t == 0) ? 0 : part[t - 1];
    for (int i = beg; i < end; i++) {
        g_rowptr[i] = base;
        g_cursor[i] = base;
        base += g_deg[i];
        g_dinv[i] = rsqrtf((float)g_deg[i] + 1.0f);  // +1 = self loop
    }
    if (t == SCAN_T - 1) g_rowptr[N] = E;
}

// ---- scatter edges into CSR buckets by dst ----
__global__ void scatter_kernel(int E) {
    int e = blockIdx.x * blockDim.x + threadIdx.x;
    if (e < E) {
        int pos = atomicAdd(&g_cursor[g_dst[e]], 1);
        g_csr[pos] = g_src[e];
    }
}

// ---- zs[row,:] = z[row,:] * dinv[row]  (also dtype-normalizes to f32) -> g_agg1 ----
__global__ void zscale_kernel(const void* __restrict__ z, int N) {
    int i = blockIdx.x * blockDim.x + threadIdx.x;
    if (i < N * IN_DIM) {
        int row = i >> 6;
        g_agg1[i] = loadx(z, i, g_in_f32) * g_dinv[row];
    }
}

// ---- layer-1 aggregation on 64-dim zs (S z): wave per node -> g_hs1 ----
__global__ void aggz_kernel(int N) {
    int wid = (blockIdx.x * blockDim.x + threadIdx.x) >> 6;
    if (wid >= N) return;
    wid = __builtin_amdgcn_readfirstlane(wid);
    int lane = threadIdx.x & 63;
    const float* zs = g_agg1;
    float a0 = zs[(size_t)wid * 64 + lane];  // self-loop term
    float a1 = 0.f, a2 = 0.f, a3 = 0.f;
    int beg = g_rowptr[wid], end = g_rowptr[wid + 1];
    int e = beg;
    for (; e + 4 <= end; e += 4) {
        int s0 = g_csr[e], s1 = g_csr[e + 1], s2 = g_csr[e + 2], s3 = g_csr[e + 3];
        a0 += zs[(size_t)s0 * 64 + lane];
        a1 += zs[(size_t)s1 * 64 + lane];
        a2 += zs[(size_t)s2 * 64 + lane];
        a3 += zs[(size_t)s3 * 64 + lane];
    }
    for (; e < end; e++) a0 += zs[(size_t)g_csr[e] * 64 + lane];
    float acc = (a0 + a1) + (a2 + a3);
    g_hs1[(size_t)wid * 64 + lane] = acc * g_dinv[wid];
}

// ---- h = relu(aggz @ W1 + b1): 32 rows/block, 4x4 micro-tile -> g_agg1 (N x 128) ----
__global__ __launch_bounds__(256) void gemm1_kernel(const void* __restrict__ W1,
                                                    const void* __restrict__ b1, int N) {
    __shared__ float Ws[IN_DIM * HID_DIM];   // 32 KB
    __shared__ float Zs[IN_DIM * 33];        // transposed 64k x 32r, pad 33 -> 8448 B
    int t = threadIdx.x;
    int f32 = g_in_f32;
    for (int i = t; i < IN_DIM * HID_DIM; i += 256) Ws[i] = loadx(W1, i, f32);
    int row0 = blockIdx.x * 32;
    const float* aggz = g_hs1;
    for (int i = t; i < 32 * IN_DIM; i += 256) {
        int r = i >> 6, k = i & 63;
        int row = row0 + r;
        Zs[k * 33 + r] = (row < N) ? aggz[(size_t)row * IN_DIM + k] : 0.f;
    }
    __syncthreads();
    int cg = t & 31, rg = t >> 5;  // 32 colgroups x 8 rowgroups
    int c0 = cg * 4, r0 = rg * 4;
    float acc[4][4] = {};
#pragma unroll 8
    for (int k = 0; k < IN_DIM; k++) {
        float b[4];
        *(float4*)b = *(const float4*)&Ws[k * HID_DIM + c0];
        float a[4];
        a[0] = Zs[k * 33 + r0];
        a[1] = Zs[k * 33 + r0 + 1];
        a[2] = Zs[k * 33 + r0 + 2];
        a[3] = Zs[k * 33 + r0 + 3];
#pragma unroll
        for (int i = 0; i < 4; i++)
#pragma unroll
            for (int j = 0; j < 4; j++) acc[i][j] = fmaf(a[i], b[j], acc[i][j]);
    }
    float bias[4];
#pragma unroll
    for (int j = 0; j < 4; j++) bias[j] = loadx(b1, c0 + j, f32);
#pragma unroll
    for (int i = 0; i < 4; i++) {
        int row = row0 + r0 + i;
        if (row < N) {
            float4 v;
            v.x = fmaxf(acc[i][0] + bias[0], 0.f);
            v.y = fmaxf(acc[i][1] + bias[1], 0.f);
            v.z = fmaxf(acc[i][2] + bias[2], 0.f);
            v.w = fmaxf(acc[i][3] + bias[3], 0.f);
            *(float4*)&g_agg1[(size_t)row * HID_DIM + c0] = v;
        }
    }
}

// ---- hs2 = (h @ W2) * dinv: 64 rows/block, K split 2x64, 4x4 micro-tile -> g_hs1 ----
__global__ __launch_bounds__(256) void gemm2_kernel(const void* __restrict__ W2, int N) {
    __shared__ float Ws[HID_DIM * OUT_DIM];  // 32 KB
    __shared__ float Zs[64 * 65];            // transposed 64k x 64r, pad 65 -> 16640 B
    int t = threadIdx.x;
    int f32 = g_in_f32;
    for (int i = t; i < HID_DIM * OUT_DIM; i += 256) Ws[i] = loadx(W2, i, f32);
    int row0 = blockIdx.x * 64;
    int cg = t & 15, rg = t >> 4;  // 16 colgroups x 16 rowgroups
    int c0 = cg * 4, r0 = rg * 4;
    float acc[4][4] = {};
    for (int kh = 0; kh < 2; kh++) {
        __syncthreads();
        for (int i = t; i < 64 * 64; i += 256) {
            int r = i >> 6, k2 = i & 63;
            int row = row0 + r;
            Zs[k2 * 65 + r] = (row < N) ? g_agg1[(size_t)row * HID_DIM + kh * 64 + k2] : 0.f;
        }
        __syncthreads();
#pragma unroll 8
        for (int k2 = 0; k2 < 64; k2++) {
            float b[4];
            *(float4*)b = *(const float4*)&Ws[(kh * 64 + k2) * OUT_DIM + c0];
            float a[4];
            a[0] = Zs[k2 * 65 + r0];
            a[1] = Zs[k2 * 65 + r0 + 1];
            a[2] = Zs[k2 * 65 + r0 + 2];
            a[3] = Zs[k2 * 65 + r0 + 3];
#pragma unroll
            for (int i = 0; i < 4; i++)
#pragma unroll
                for (int j = 0; j < 4; j++) acc[i][j] = fmaf(a[i], b[j], acc[i][j]);
        }
    }
#pragma unroll
    for (int i = 0; i < 4; i++) {
        int row = row0 + r0 + i;
        if (row < N) {
            float dn = g_dinv[row];
            float4 v;
            v.x = acc[i][0] * dn;
            v.y = acc[i][1] * dn;
            v.z = acc[i][2] * dn;
            v.w = acc[i][3] * dn;
            *(float4*)&g_hs1[(size_t)row * OUT_DIM + c0] = v;
        }
    }
}

// ---- layer-2 aggregation: wave per node, float/lane; fused bias + store ----
__global__ void agg2_kernel(const void* __restrict__ b2, void* __restrict__ out, int N) {
    int wid = (blockIdx.x * blockDim.x + threadIdx.x) >> 6;
    if (wid >= N) return;
    wid = __builtin_amdgcn_readfirstlane(wid);
    int lane = threadIdx.x & 63;
    const float* hs = g_hs1;  // row = 64 floats
    float a0 = hs[(size_t)wid * 64 + lane];  // self-loop term
    float a1 = 0.f, a2 = 0.f, a3 = 0.f;
    int beg = g_rowptr[wid], end = g_rowptr[wid + 1];
    int e = beg;
    for (; e + 4 <= end; e += 4) {
        int s0 = g_csr[e], s1 = g_csr[e + 1], s2 = g_csr[e + 2], s3 = g_csr[e + 3];
        a0 += hs[(size_t)s0 * 64 + lane];
        a1 += hs[(size_t)s1 * 64 + lane];
        a2 += hs[(size_t)s2 * 64 + lane];
        a3 += hs[(size_t)s3 * 64 + lane];
    }
    for (; e < end; e++) a0 += hs[(size_t)g_csr[e] * 64 + lane];
    float acc = (a0 + a1) + (a2 + a3);
    int f32 = g_in_f32;
    float v = acc * g_dinv[wid] + loadx(b2, lane, f32);
    if (f32) ((float*)out)[(size_t)wid * 64 + lane] = v;
    else ((__hip_bfloat16*)out)[(size_t)wid * 64 + lane] = __float2bfloat16(v);
}

extern "C" void kernel_launch(void* const* d_in, const int* in_sizes, int n_in,
                              void* d_out, int out_size, void* d_ws, size_t ws_size,
                              hipStream_t stream) {
    const void* z  = d_in[0];
    const void* ei = d_in[1];
    const void* W1 = d_in[2];
    const void* b1 = d_in[3];
    const void* W2 = d_in[4];
    const void* b2 = d_in[5];

    const int N = in_sizes[0] / IN_DIM;  // 50000
    const int E = in_sizes[1] / 2;       // 800000

    detect_kernel<<<1, 256, 0, stream>>>((const unsigned short*)z, (const unsigned int*)ei, E);
    convert_kernel<<<(E + 255) / 256, 256, 0, stream>>>(ei, E);
    scan_kernel<<<1, SCAN_T, 0, stream>>>(N, E);
    scatter_kernel<<<(E + 255) / 256, 256, 0, stream>>>(E);

    zscale_kernel<<<(N * IN_DIM + 255) / 256, 256, 0, stream>>>(z, N);
    aggz_kernel<<<(N * 64 + 255) / 256, 256, 0, stream>>>(N);
    gemm1_kernel<<<(N + 31) / 32, 256, 0, stream>>>(W1, b1, N);

    gemm2_kernel<<<(N + 63) / 64, 256, 0, stream>>>(W2, N);
    agg2_kernel<<<(N * 64 + 255) / 256, 256, 0, stream>>>(b2, d_out, N);
}

// Round 2
// 361.309 us; speedup vs baseline: 1.8612x; 1.3513x over previous
//
#include <hip/hip_runtime.h>
#include <hip/hip_bf16.h>

#define N_NODES 50000
#define N_EDGES 800000
#define IN_DIM 64
#define HID_DIM 128
#define OUT_DIM 64
#define NBLK ((N_NODES + 255) / 256)  // 196 scan blocks

// ---- device-global scratch (no ws_size dependence) ----
__device__ int g_in_f32;
__device__ int g_is64;
__device__ int g_src[N_EDGES];
__device__ int g_dst[N_EDGES];
__device__ int g_csr[N_EDGES];
__device__ int g_deg[N_NODES];
__device__ int g_rowptr[N_NODES + 1];
__device__ int g_cursor[N_NODES];
__device__ int g_bsum[NBLK];
__device__ int g_boff[NBLK];
__device__ float g_dinv[N_NODES];
__device__ __align__(16) float g_hs1[(size_t)N_NODES * HID_DIM];   // aggz (N*64), later hs2 (N*64)
__device__ __align__(16) float g_agg1[(size_t)N_NODES * HID_DIM];  // zs (N*64), later h (N*128)

__device__ __forceinline__ float loadx(const void* p, int i, int f32) {
    if (f32) return ((const float*)p)[i];
    unsigned int u = ((unsigned int)((const unsigned short*)p)[i]) << 16;
    return __uint_as_float(u);
}

// ---- dtype / index-width detection (data-driven, deterministic); zero deg ----
__global__ void detect_kernel(const unsigned short* __restrict__ zw,
                              const unsigned int* __restrict__ ew, int E) {
    __shared__ int s_f32, s_nz;
    if (threadIdx.x == 0) { s_f32 = 0; s_nz = 0; }
    __syncthreads();
    int hit = 0;
    for (int k = 0; k < 64; k++) {
        int i = 2 * ((threadIdx.x * 64 + k) * 97);
        if (((zw[i] >> 7) & 0xFF) == 0xFF) hit = 1;
    }
    if (hit) atomicOr(&s_f32, 1);
    int nz = 0;
    int step = E / 4096;
    for (int k = 0; k < 4; k++) {
        int idx = 1 + 2 * ((threadIdx.x * 4 + k) * step);
        if (ew[idx] != 0) nz = 1;
    }
    if (nz) atomicOr(&s_nz, 1);
    for (int i = threadIdx.x; i < N_NODES; i += 256) g_deg[i] = 0;
    __syncthreads();
    if (threadIdx.x == 0) { g_in_f32 = s_f32; g_is64 = (s_nz == 0) ? 1 : 0; }
}

// ---- normalize edge_index to int32 + fused degree count ----
__global__ void convert_kernel(const void* __restrict__ ei, int E) {
    int e = blockIdx.x * blockDim.x + threadIdx.x;
    if (e < E) {
        int s, d;
        if (g_is64) {
            const long long* p = (const long long*)ei;
            s = (int)p[e];
            d = (int)p[E + e];
        } else {
            const int* p = (const int*)ei;
            s = p[e];
            d = p[E + e];
        }
        g_src[e] = s;
        g_dst[e] = d;
        atomicAdd(&g_deg[d], 1);
    }
}

// ---- phase A: per-block exclusive scan of deg; dinv fused ----
__global__ __launch_bounds__(256) void localscan_kernel(int N) {
    __shared__ int sc[256];
    int t = threadIdx.x;
    int idx = blockIdx.x * 256 + t;
    int d = (idx < N) ? g_deg[idx] : 0;
    sc[t] = d;
    __syncthreads();
    for (int off = 1; off < 256; off <<= 1) {
        int v = (t >= off) ? sc[t - off] : 0;
        __syncthreads();
        sc[t] += v;
        __syncthreads();
    }
    if (idx < N) {
        g_rowptr[idx] = sc[t] - d;  // local exclusive prefix (offset added in phase C)
        g_dinv[idx] = rsqrtf((float)d + 1.0f);  // +1 = self loop
    }
    if (t == 255) g_bsum[blockIdx.x] = sc[255];
}

// ---- phase B: single small block scans block sums -> g_boff ----
__global__ __launch_bounds__(256) void bscan_kernel(int N, int E) {
    __shared__ int sc[256];
    int t = threadIdx.x;
    int v = (t < NBLK) ? g_bsum[t] : 0;
    sc[t] = v;
    __syncthreads();
    for (int off = 1; off < 256; off <<= 1) {
        int u = (t >= off) ? sc[t - off] : 0;
        __syncthreads();
        sc[t] += u;
        __syncthreads();
    }
    if (t < NBLK) g_boff[t] = sc[t] - v;
    if (t == 0) g_rowptr[N] = E;
}

// ---- phase C: add block offsets; finalize rowptr + cursor ----
__global__ __launch_bounds__(256) void addoff_kernel(int N) {
    int idx = blockIdx.x * 256 + threadIdx.x;
    if (idx < N) {
        int base = g_rowptr[idx] + g_boff[blockIdx.x];
        g_rowptr[idx] = base;
        g_cursor[idx] = base;
    }
}

// ---- scatter edges into CSR buckets by dst ----
__global__ void scatter_kernel(int E) {
    int e = blockIdx.x * blockDim.x + threadIdx.x;
    if (e < E) {
        int pos = atomicAdd(&g_cursor[g_dst[e]], 1);
        g_csr[pos] = g_src[e];
    }
}

// ---- zs[row,:] = z[row,:] * dinv[row]  (also dtype-normalizes to f32) -> g_agg1 ----
__global__ void zscale_kernel(const void* __restrict__ z, int N) {
    int i = blockIdx.x * blockDim.x + threadIdx.x;
    if (i < N * IN_DIM) {
        int row = i >> 6;
        g_agg1[i] = loadx(z, i, g_in_f32) * g_dinv[row];
    }
}

// ---- layer-1 aggregation on 64-dim zs (S z): wave per node -> g_hs1 ----
__global__ void aggz_kernel(int N) {
    int wid = (blockIdx.x * blockDim.x + threadIdx.x) >> 6;
    if (wid >= N) return;
    wid = __builtin_amdgcn_readfirstlane(wid);
    int lane = threadIdx.x & 63;
    const float* zs = g_agg1;
    float a0 = zs[(size_t)wid * 64 + lane];  // self-loop term
    float a1 = 0.f, a2 = 0.f, a3 = 0.f;
    int beg = g_rowptr[wid], end = g_rowptr[wid + 1];
    int e = beg;
    for (; e + 4 <= end; e += 4) {
        int s0 = g_csr[e], s1 = g_csr[e + 1], s2 = g_csr[e + 2], s3 = g_csr[e + 3];
        a0 += zs[(size_t)s0 * 64 + lane];
        a1 += zs[(size_t)s1 * 64 + lane];
        a2 += zs[(size_t)s2 * 64 + lane];
        a3 += zs[(size_t)s3 * 64 + lane];
    }
    for (; e < end; e++) a0 += zs[(size_t)g_csr[e] * 64 + lane];
    float acc = (a0 + a1) + (a2 + a3);
    g_hs1[(size_t)wid * 64 + lane] = acc * g_dinv[wid];
}

// ---- h = relu(aggz @ W1 + b1): 32 rows/block, 4x4 micro-tile -> g_agg1 (N x 128) ----
__global__ __launch_bounds__(256) void gemm1_kernel(const void* __restrict__ W1,
                                                    const void* __restrict__ b1, int N) {
    __shared__ float Ws[IN_DIM * HID_DIM];   // 32 KB
    __shared__ float Zs[IN_DIM * 33];        // transposed 64k x 32r, pad 33 -> 8448 B
    int t = threadIdx.x;
    int f32 = g_in_f32;
    for (int i = t; i < IN_DIM * HID_DIM; i += 256) Ws[i] = loadx(W1, i, f32);
    int row0 = blockIdx.x * 32;
    const float* aggz = g_hs1;
    for (int i = t; i < 32 * IN_DIM; i += 256) {
        int r = i >> 6, k = i & 63;
        int row = row0 + r;
        Zs[k * 33 + r] = (row < N) ? aggz[(size_t)row * IN_DIM + k] : 0.f;
    }
    __syncthreads();
    int cg = t & 31, rg = t >> 5;  // 32 colgroups x 8 rowgroups
    int c0 = cg * 4, r0 = rg * 4;
    float acc[4][4] = {};
#pragma unroll 8
    for (int k = 0; k < IN_DIM; k++) {
        float b[4];
        *(float4*)b = *(const float4*)&Ws[k * HID_DIM + c0];
        float a[4];
        a[0] = Zs[k * 33 + r0];
        a[1] = Zs[k * 33 + r0 + 1];
        a[2] = Zs[k * 33 + r0 + 2];
        a[3] = Zs[k * 33 + r0 + 3];
#pragma unroll
        for (int i = 0; i < 4; i++)
#pragma unroll
            for (int j = 0; j < 4; j++) acc[i][j] = fmaf(a[i], b[j], acc[i][j]);
    }
    float bias[4];
#pragma unroll
    for (int j = 0; j < 4; j++) bias[j] = loadx(b1, c0 + j, f32);
#pragma unroll
    for (int i = 0; i < 4; i++) {
        int row = row0 + r0 + i;
        if (row < N) {
            float4 v;
            v.x = fmaxf(acc[i][0] + bias[0], 0.f);
            v.y = fmaxf(acc[i][1] + bias[1], 0.f);
            v.z = fmaxf(acc[i][2] + bias[2], 0.f);
            v.w = fmaxf(acc[i][3] + bias[3], 0.f);
            *(float4*)&g_agg1[(size_t)row * HID_DIM + c0] = v;
        }
    }
}

// ---- hs2 = (h @ W2) * dinv: 64 rows/block, K split 2x64, 4x4 micro-tile -> g_hs1 ----
__global__ __launch_bounds__(256) void gemm2_kernel(const void* __restrict__ W2, int N) {
    __shared__ float Ws[HID_DIM * OUT_DIM];  // 32 KB
    __shared__ float Zs[64 * 65];            // transposed 64k x 64r, pad 65 -> 16640 B
    int t = threadIdx.x;
    int f32 = g_in_f32;
    for (int i = t; i < HID_DIM * OUT_DIM; i += 256) Ws[i] = loadx(W2, i, f32);
    int row0 = blockIdx.x * 64;
    int cg = t & 15, rg = t >> 4;  // 16 colgroups x 16 rowgroups
    int c0 = cg * 4, r0 = rg * 4;
    float acc[4][4] = {};
    for (int kh = 0; kh < 2; kh++) {
        __syncthreads();
        for (int i = t; i < 64 * 64; i += 256) {
            int r = i >> 6, k2 = i & 63;
            int row = row0 + r;
            Zs[k2 * 65 + r] = (row < N) ? g_agg1[(size_t)row * HID_DIM + kh * 64 + k2] : 0.f;
        }
        __syncthreads();
#pragma unroll 8
        for (int k2 = 0; k2 < 64; k2++) {
            float b[4];
            *(float4*)b = *(const float4*)&Ws[(kh * 64 + k2) * OUT_DIM + c0];
            float a[4];
            a[0] = Zs[k2 * 65 + r0];
            a[1] = Zs[k2 * 65 + r0 + 1];
            a[2] = Zs[k2 * 65 + r0 + 2];
            a[3] = Zs[k2 * 65 + r0 + 3];
#pragma unroll
            for (int i = 0; i < 4; i++)
#pragma unroll
                for (int j = 0; j < 4; j++) acc[i][j] = fmaf(a[i], b[j], acc[i][j]);
        }
    }
#pragma unroll
    for (int i = 0; i < 4; i++) {
        int row = row0 + r0 + i;
        if (row < N) {
            float dn = g_dinv[row];
            float4 v;
            v.x = acc[i][0] * dn;
            v.y = acc[i][1] * dn;
            v.z = acc[i][2] * dn;
            v.w = acc[i][3] * dn;
            *(float4*)&g_hs1[(size_t)row * OUT_DIM + c0] = v;
        }
    }
}

// ---- layer-2 aggregation: wave per node, float/lane; fused bias + store ----
__global__ void agg2_kernel(const void* __restrict__ b2, void* __restrict__ out, int N) {
    int wid = (blockIdx.x * blockDim.x + threadIdx.x) >> 6;
    if (wid >= N) return;
    wid = __builtin_amdgcn_readfirstlane(wid);
    int lane = threadIdx.x & 63;
    const float* hs = g_hs1;  // row = 64 floats
    float a0 = hs[(size_t)wid * 64 + lane];  // self-loop term
    float a1 = 0.f, a2 = 0.f, a3 = 0.f;
    int beg = g_rowptr[wid], end = g_rowptr[wid + 1];
    int e = beg;
    for (; e + 4 <= end; e += 4) {
        int s0 = g_csr[e], s1 = g_csr[e + 1], s2 = g_csr[e + 2], s3 = g_csr[e + 3];
        a0 += hs[(size_t)s0 * 64 + lane];
        a1 += hs[(size_t)s1 * 64 + lane];
        a2 += hs[(size_t)s2 * 64 + lane];
        a3 += hs[(size_t)s3 * 64 + lane];
    }
    for (; e < end; e++) a0 += hs[(size_t)g_csr[e] * 64 + lane];
    float acc = (a0 + a1) + (a2 + a3);
    int f32 = g_in_f32;
    float v = acc * g_dinv[wid] + loadx(b2, lane, f32);
    if (f32) ((float*)out)[(size_t)wid * 64 + lane] = v;
    else ((__hip_bfloat16*)out)[(size_t)wid * 64 + lane] = __float2bfloat16(v);
}

extern "C" void kernel_launch(void* const* d_in, const int* in_sizes, int n_in,
                              void* d_out, int out_size, void* d_ws, size_t ws_size,
                              hipStream_t stream) {
    const void* z  = d_in[0];
    const void* ei = d_in[1];
    const void* W1 = d_in[2];
    const void* b1 = d_in[3];
    const void* W2 = d_in[4];
    const void* b2 = d_in[5];

    const int N = in_sizes[0] / IN_DIM;  // 50000
    const int E = in_sizes[1] / 2;       // 800000

    detect_kernel<<<1, 256, 0, stream>>>((const unsigned short*)z, (const unsigned int*)ei, E);
    convert_kernel<<<(E + 255) / 256, 256, 0, stream>>>(ei, E);
    localscan_kernel<<<NBLK, 256, 0, stream>>>(N);
    bscan_kernel<<<1, 256, 0, stream>>>(N, E);
    addoff_kernel<<<NBLK, 256, 0, stream>>>(N);
    scatter_kernel<<<(E + 255) / 256, 256, 0, stream>>>(E);

    zscale_kernel<<<(N * IN_DIM + 255) / 256, 256, 0, stream>>>(z, N);
    aggz_kernel<<<(N * 64 + 255) / 256, 256, 0, stream>>>(N);
    gemm1_kernel<<<(N + 31) / 32, 256, 0, stream>>>(W1, b1, N);

    gemm2_kernel<<<(N + 63) / 64, 256, 0, stream>>>(W2, N);
    agg2_kernel<<<(N * 64 + 255) / 256, 256, 0, stream>>>(b2, d_out, N);
}